// Round 5
// baseline (784.482 us; speedup 1.0000x reference)
//
#include <hip/hip_runtime.h>
#include <math.h>

// Problem constants (reference: B,N,M,C = 4,4096,4096,256)
#define BB 4
#define BN 4096          // N == M == 4096
constexpr float T2      = 0.04f;                     // DIST_THRESH^2
constexpr float INV_EPS = (float)(1.0 / 0.01000001); // 1/(EPSILON + 1e-8)

__device__ __forceinline__ int cell_of(float x, float y) {
  int cx = (int)(x * 5.0f); cx = cx < 0 ? 0 : (cx > 4 ? 4 : cx);
  int cy = (int)(y * 5.0f); cy = cy < 0 ? 0 : (cy > 4 ? 4 : cy);
  return cy * 5 + cx;
}

// ---------------------------------------------------------------- binning ---
__global__ void k_count(const float* __restrict__ tlocs, const float* __restrict__ slocs,
                        int* __restrict__ counts_t, int* __restrict__ counts_s) {
  int gid = blockIdx.x * 256 + threadIdx.x;       // covers B*(M+N) = 32768
  if (gid < BB * BN) {
    int b = gid >> 12;
    atomicAdd(&counts_t[b * 32 + cell_of(tlocs[gid * 2], tlocs[gid * 2 + 1])], 1);
  } else {
    int g = gid - BB * BN;
    int b = g >> 12;
    atomicAdd(&counts_s[b * 32 + cell_of(slocs[g * 2], slocs[g * 2 + 1])], 1);
  }
}

// Scan 25 cells, scatter indices AND build cell-sorted packs (x, y, 0, valid).
__global__ void k_scan_scatter(const float* __restrict__ tlocs, const float* __restrict__ slocs,
                               const int* __restrict__ tmask, const int* __restrict__ smask,
                               const int* __restrict__ counts_t, const int* __restrict__ counts_s,
                               int* __restrict__ starts_t, int* __restrict__ starts_s,
                               int* __restrict__ perm_t, int* __restrict__ perm_s,
                               float4* __restrict__ t_sorted, float4* __restrict__ s_sorted) {
  const int which = blockIdx.x & 1, b = blockIdx.x >> 1;   // grid = 2*B
  const float* locs = which ? slocs : tlocs;
  const int*   mask = which ? smask : tmask;
  const int* counts = which ? counts_s : counts_t;
  int* starts       = which ? starts_s : starts_t;
  int* perm         = which ? perm_s : perm_t;
  float4* pack      = which ? s_sorted : t_sorted;
  __shared__ int st[26];
  __shared__ int cur[25];
  if (threadIdx.x == 0) {
    int acc = 0;
    for (int c = 0; c < 25; c++) { st[c] = acc; acc += counts[b * 32 + c]; }
    st[25] = acc;                                   // == 4096
  }
  __syncthreads();
  if (threadIdx.x < 25) cur[threadIdx.x] = st[threadIdx.x];
  if (threadIdx.x < 26) starts[b * 32 + threadIdx.x] = st[threadIdx.x];
  __syncthreads();
  for (int i = threadIdx.x; i < BN; i += 256) {
    float x = locs[(b * BN + i) * 2], y = locs[(b * BN + i) * 2 + 1];
    int pos = atomicAdd(&cur[cell_of(x, y)], 1);
    perm[b * BN + pos] = i;
    pack[b * BN + pos] = make_float4(x, y, 0.f, mask[b * BN + i] ? 1.f : 0.f);
  }
}

// ------------------------------------------------------ sparse Sinkhorn -----
// One wave per row, 16384 waves. Branchless MLP fix vs r4: sorted arrays carry
// an 8 KB padded tail, so all UNR loads issue UNCONDITIONALLY (no exec-mask
// serialization); the j<r1 bound is applied only in the math mask. UNR=4 keeps
// VGPR <= ~64 (8 waves/SIMD). Same verified sparse mirror semantics
// (absmax 9.8e-4): finite terms only in the 3x3 box; NEG_INF leak rows counted
// into Zout, folded into the next phase as Z copies of exp(0)=1.
#define UNR 4
__global__ __launch_bounds__(256) void k_sink(const float4* __restrict__ opp,
                                              float4* __restrict__ own,
                                              const int* __restrict__ opp_starts,
                                              const int* __restrict__ Zin,
                                              int* __restrict__ Zout,
                                              int zero_invalid) {
  const int row  = blockIdx.x * 4 + (threadIdx.x >> 6);    // 0..16383
  const int b    = row >> 12;
  const int lane = threadIdx.x & 63;
  const float4 me = own[row];
  float mrun = -1e30f, srun = 0.f;
  if (me.w != 0.f) {                                       // invalid rows: no finite terms
    const int cell = cell_of(me.x, me.y);
    const int cy = cell / 5, cx = cell % 5;
    const int ry0 = max(cy - 1, 0), ry1 = min(cy + 1, 4);
    const int rx0 = max(cx - 1, 0), rx1 = min(cx + 1, 4);
    const float4* oppB = opp + b * BN;
    for (int ry = ry0; ry <= ry1; ry++) {
      const int r0 = opp_starts[b * 32 + ry * 5 + rx0];
      const int r1 = opp_starts[b * 32 + ry * 5 + rx1 + 1];  // contiguous row-major cells
      for (int base = r0 + lane; base < r1; base += 64 * UNR) {
        float4 buf[UNR];
        #pragma unroll
        for (int u = 0; u < UNR; u++)                      // unconditional: padded tail
          buf[u] = oppB[base + u * 64];
        #pragma unroll
        for (int u = 0; u < UNR; u++) {
          const int j = base + u * 64;
          float4 o = buf[u];
          float dx = me.x - o.x, dy = me.y - o.y;
          float d2 = fmaf(dx, dx, dy * dy);
          bool  c  = (j < r1) && (d2 < T2) && (o.w != 0.f);
          float t  = c ? fmaf(d2, -INV_EPS, o.z) : -3e30f; // masked: exp -> exactly 0
          float d  = t - mrun;
          float e  = __expf(-fabsf(d));
          if (d > 0.f) { srun = fmaf(srun, e, 1.f); mrun = t; }
          else         { srun += e; }
        }
      }
    }
  }
  for (int off = 32; off > 0; off >>= 1) {
    float om = __shfl_down(mrun, off);
    float os = __shfl_down(srun, off);
    float nm = fmaxf(mrun, om);
    srun = srun * __expf(mrun - nm) + os * __expf(om - nm);
    mrun = nm;
  }
  if (lane == 0) {
    const int Z = Zin[b];
    float m0 = mrun, s = srun;
    if (Z > 0) {                     // fold leak terms (t == 0, count Z)
      m0 = fmaxf(mrun, 0.f);
      s  = srun * __expf(mrun - m0) + (float)Z * __expf(-m0);
    }
    float val = (s > 0.f) ? -(m0 + logf(s)) : 1.0e9f;      // empty row -> exactly 1e9f
    if (zero_invalid && me.w == 0.f) val = 0.f;
    own[row] = make_float4(me.x, me.y, val, me.w);
    if (val == 1.0e9f) atomicAdd(&Zout[b], 1);
  }
}

// ------------------------------------------------- sparse attn @ feats ------
// Occupancy-driven redesign (r4 pipeline reverted). Block = (batch, cell,
// 32-target chunk, box cell-row rp, 128-channel half) -> ~2700 active blocks.
// No fL tile: MAC reads feats straight from global (L2-resident; each group-of-4
// load coalesces to 512 B, deduped across the two tmg halves). LDS ~3.3 KB,
// 2 barriers per 16-source chunk. Partials combined with atomicAdd (out zeroed
// first; each element receives <=3 adds). has_source/target_valid gates are
// redundant: attn == 0 exactly wherever the reference gates would zero.
#define MAXCH 12   // 12*32 = 384 targets/cell upper bound (mean 164, sigma 13)

__global__ __launch_bounds__(256) void k_out(
    const float4* __restrict__ featsF4, const float4* __restrict__ t_sorted,
    const float4* __restrict__ s_sorted, const int* __restrict__ perm_t,
    const int* __restrict__ perm_s, const int* __restrict__ starts_t,
    const int* __restrict__ starts_s, float* __restrict__ out) {
  const int z    = blockIdx.z;                  // b*6 + rp*2 + chsel
  const int b    = z / 6;
  const int rp   = (z % 6) >> 1;                // 0..2: box cell-row
  const int chO  = (z & 1) << 5;                // float4 channel offset: 0 / 32
  const int cell = blockIdx.y;
  const int cy = cell / 5, cx = cell % 5;
  const int ry = cy + rp - 1;
  if (ry < 0 || ry > 4) return;                 // uniform early-exits only
  const int t0 = starts_t[b * 32 + cell], t1 = starts_t[b * 32 + cell + 1];
  const int base = t0 + blockIdx.x * 32;
  if (base >= t1) return;
  const int rx0 = max(cx - 1, 0), rx1 = min(cx + 1, 4);
  const int s0 = starts_s[b * 32 + ry * 5 + rx0];
  const int s1 = starts_s[b * 32 + ry * 5 + rx1 + 1];
  if (s0 >= s1) return;
  const int nt      = min(32, t1 - base);
  const int nchunks = (s1 - s0 + 15) >> 4;

  __shared__ float4 tL[32];                     // x, y, u, tv
  __shared__ int    morg[32];
  __shared__ float4 sL[2][16];                  // x, y, v, sv (dbuf)
  __shared__ int    sorgL[2][16];
  __shared__ __align__(16) float attnF[512];    // attn[nn*32 + tm]

  const int tid = threadIdx.x;
  const int tmg = tid >> 5, chg = tid & 31;

  if (tid < 32) {
    if (tid < nt) {
      tL[tid]   = t_sorted[b * BN + base + tid];
      morg[tid] = perm_t[b * BN + base + tid];
    } else {
      tL[tid]   = make_float4(0.f, 0.f, 0.f, 0.f);   // tv=0 -> attn 0
      morg[tid] = 0;
    }
  }
  if (tid < 16) {                               // stage sL[0]
    int j = s0 + tid;
    if (j < s1) {
      sL[0][tid]    = s_sorted[b * BN + j];
      sorgL[0][tid] = perm_s[b * BN + j];
    } else {
      sL[0][tid]    = make_float4(1e9f, 1e9f, 0.f, 0.f);
      sorgL[0][tid] = 0;
    }
  }
  __syncthreads();
  {                                             // stage attn(0): 2 entries/thread
    float2 a2;
    #pragma unroll
    for (int q = 0; q < 2; q++) {
      int e = tid * 2 + q, nn = e >> 5, tm = e & 31;
      float4 t4 = tL[tm];
      float4 s4 = sL[0][nn];
      float dx = t4.x - s4.x, dy = t4.y - s4.y;
      float d2 = fmaf(dx, dx, dy * dy);
      bool  c  = (d2 < T2) && (s4.w != 0.f) && (t4.w != 0.f);
      (&a2.x)[q] = c ? __expf(fmaf(d2, -INV_EPS, t4.z + s4.z)) : 0.f;
    }
    ((float2*)attnF)[tid] = a2;
  }
  __syncthreads();

  float acc[4][4];
  #pragma unroll
  for (int i = 0; i < 4; i++)
    #pragma unroll
    for (int j = 0; j < 4; j++) acc[i][j] = 0.f;

  const int fbase = (b << 12) << 6;             // feats batch base (float4 units)
  for (int i = 0; i < nchunks; i++) {
    const int cur = i & 1, nxt = cur ^ 1;
    const bool more = (i + 1) < nchunks;
    if (more && tid < 16) {                     // prefetch sL[nxt]; overlaps MAC
      int j = s0 + (i + 1) * 16 + tid;
      if (j < s1) {
        sL[nxt][tid]    = s_sorted[b * BN + j];
        sorgL[nxt][tid] = perm_s[b * BN + j];
      } else {
        sL[nxt][tid]    = make_float4(1e9f, 1e9f, 0.f, 0.f);
        sorgL[nxt][tid] = 0;
      }
    }
    #pragma unroll                              // MAC: 4 groups of 4 sources
    for (int g = 0; g < 4; g++) {
      float4 fr[4];
      #pragma unroll
      for (int q = 0; q < 4; q++) {             // 4 independent L2 loads in flight
        int so = sorgL[cur][g * 4 + q];
        fr[q] = featsF4[fbase + (so << 6) + chO + chg];
      }
      #pragma unroll
      for (int q = 0; q < 4; q++) {
        const int nn = g * 4 + q;
        const float4 av = *(const float4*)&attnF[(nn << 5) + (tmg << 2)];
        #pragma unroll
        for (int ii = 0; ii < 4; ii++) {
          float a = (&av.x)[ii];
          acc[ii][0] = fmaf(a, fr[q].x, acc[ii][0]);
          acc[ii][1] = fmaf(a, fr[q].y, acc[ii][1]);
          acc[ii][2] = fmaf(a, fr[q].z, acc[ii][2]);
          acc[ii][3] = fmaf(a, fr[q].w, acc[ii][3]);
        }
      }
    }
    __syncthreads();                            // B1: MAC done; sL[nxt] visible
    if (more) {                                 // stage attn(i+1)
      float2 a2;
      #pragma unroll
      for (int q = 0; q < 2; q++) {
        int e = tid * 2 + q, nn = e >> 5, tm = e & 31;
        float4 t4 = tL[tm];
        float4 s4 = sL[nxt][nn];
        float dx = t4.x - s4.x, dy = t4.y - s4.y;
        float d2 = fmaf(dx, dx, dy * dy);
        bool  c  = (d2 < T2) && (s4.w != 0.f) && (t4.w != 0.f);
        (&a2.x)[q] = c ? __expf(fmaf(d2, -INV_EPS, t4.z + s4.z)) : 0.f;
      }
      ((float2*)attnF)[tid] = a2;
    }
    __syncthreads();                            // B2: attn(i+1) visible
  }

  // epilogue: atomic partial accumulation (<=3 row-pieces per element)
  #pragma unroll
  for (int i = 0; i < 4; i++) {
    int tm = (tmg << 2) + i;
    if (tm < nt) {
      float* op = out + (((b << 12) + morg[tm]) << 8) + (chO << 2) + (chg << 2);
      #pragma unroll
      for (int j = 0; j < 4; j++) atomicAdd(op + j, acc[i][j]);
    }
  }
}

// ----------------------------------------------------------------- launch ---
extern "C" void kernel_launch(void* const* d_in, const int* in_sizes, int n_in,
                              void* d_out, int out_size, void* d_ws, size_t ws_size,
                              hipStream_t stream) {
  const float* feats = (const float*)d_in[0];   // [B,N,C] f32
  const float* slocs = (const float*)d_in[1];   // [B,N,2] f32
  const float* tlocs = (const float*)d_in[2];   // [B,M,2] f32
  const int*   smask = (const int*)d_in[3];     // [B,N] int32 (bool)
  const int*   tmask = (const int*)d_in[4];     // [B,M] int32 (bool)
  float* out = (float*)d_out;

  char* ws = (char*)d_ws;                       // ~670 KB used
  int*    counts_t = (int*)(ws);                //   512 B
  int*    counts_s = (int*)(ws + 512);          //   512 B
  int*    Zc       = (int*)(ws + 1024);         //   7 slots x 4 batches
  int*    starts_t = (int*)(ws + 2048);         //   512 B
  int*    starts_s = (int*)(ws + 2560);         //   512 B
  int*    perm_t   = (int*)(ws + 4096);         //   64 KB
  int*    perm_s   = (int*)(ws + 69632);        //   64 KB
  float4* s_sorted = (float4*)(ws + 135168);    //  256 KB (x,y,v,sv) cell-sorted
  float4* t_sorted = (float4*)(ws + 397312);    //  256 KB + 8 KB padded tail
                                                //  (UNR overshoot: s_sorted spills
                                                //   into t_sorted, t_sorted into pad;
                                                //   both masked by j<r1)

  hipMemsetAsync(ws, 0, 2048, stream);          // zero cell counters + Z slots
  hipMemsetAsync(out, 0, (size_t)out_size * sizeof(float), stream);
  k_count<<<128, 256, 0, stream>>>(tlocs, slocs, counts_t, counts_s);
  k_scan_scatter<<<8, 256, 0, stream>>>(tlocs, slocs, tmask, smask,
                                        counts_t, counts_s, starts_t, starts_s,
                                        perm_t, perm_s, t_sorted, s_sorted);
  for (int it = 0; it < 3; it++) {
    // u-update: Zin = leak count of current v (slot 0 = zeros for it==0)
    k_sink<<<4096, 256, 0, stream>>>(s_sorted, t_sorted, starts_s,
                                     Zc + (it == 0 ? 0 : (2 * it) * 4),
                                     Zc + (2 * it + 1) * 4, 0);
    // v-update: Zin = leak count of u just written
    k_sink<<<4096, 256, 0, stream>>>(t_sorted, s_sorted, starts_t,
                                     Zc + (2 * it + 1) * 4,
                                     Zc + (2 * it + 2) * 4, 1);
  }
  k_out<<<dim3(MAXCH, 25, BB * 6), 256, 0, stream>>>(
      (const float4*)feats, t_sorted, s_sorted, perm_t, perm_s,
      starts_t, starts_s, out);
}